// Round 1
// baseline (434.364 us; speedup 1.0000x reference)
//
#include <hip/hip_runtime.h>
#include <cstdint>

typedef unsigned short u16;
typedef unsigned int   u32;
typedef __attribute__((ext_vector_type(8))) short  short8;
typedef __attribute__((ext_vector_type(4))) float  floatx4;

#define NPTS 524288   // B*N2*K
#define NBUK 64       // stat buckets

__device__ __forceinline__ float b2f(u16 h) { return __uint_as_float(((u32)h) << 16); }
__device__ __forceinline__ u16 f2b(float f) {
  u32 u = __float_as_uint(f);
  return (u16)((u + 0x7FFFu + ((u >> 16) & 1u)) >> 16);
}
__device__ __forceinline__ short8 ld_frag8(const u16* p) {
  union { uint2 u[2]; short8 s; } x;
  x.u[0] = *(const uint2*)(p);
  x.u[1] = *(const uint2*)(p + 4);
  return x.s;
}

// ---- prep: W -> bf16, rows padded to pitch 100, zero pad region ----
__global__ __launch_bounds__(256) void prep_w(const float* __restrict__ W0,
                                              const float* __restrict__ W1,
                                              const float* __restrict__ W2,
                                              u16* __restrict__ Wb) {
  int s = blockIdx.x * 256 + threadIdx.x;   // 25600 total
  if (s >= 25600) return;
  u16 v = 0;
  if (s < 6400)        { int o = s / 100, c = s % 100; if (c < 67) v = f2b(W0[o * 67 + c]); }
  else if (s < 12800)  { int q = s - 6400;  int o = q / 100, c = q % 100; if (c < 64) v = f2b(W1[o * 64 + c]); }
  else                 { int q = s - 12800; int o = q / 100, c = q % 100; if (c < 64) v = f2b(W2[o * 64 + c]); }
  Wb[s] = v;
}

// ---- prep: in_feature [b][c][n] f32 -> featT [b][n][c] bf16 ----
__global__ __launch_bounds__(256) void trans_feat(const float* __restrict__ inf,
                                                  u16* __restrict__ featT) {
  __shared__ float tile[32 * 33];
  int blk = blockIdx.x;                 // 4096 = 16 * 2 * 128
  int b = blk >> 8, rem = blk & 255, cc = rem >> 7, nc = rem & 127;
  int t = threadIdx.x;
  #pragma unroll
  for (int i = 0; i < 4; ++i) {
    int flat = t + i * 256;             // 1024
    int cl = flat >> 5, nl = flat & 31;
    tile[cl * 33 + nl] = inf[(size_t)((b * 64) + cc * 32 + cl) * 4096 + nc * 32 + nl];
  }
  __syncthreads();
  #pragma unroll
  for (int i = 0; i < 4; ++i) {
    int flat = t + i * 256;
    int nl = flat >> 5, cl = flat & 31;
    featT[(size_t)((b << 12) + nc * 32 + nl) * 64 + cc * 32 + cl] = f2b(tile[cl * 33 + nl]);
  }
}

// ---- prep: in_xyz [b][3][n] -> xyzT [b][n][float4] ----
__global__ __launch_bounds__(256) void trans_xyz(const float* __restrict__ ixyz,
                                                 float4* __restrict__ xyzT) {
  int g = blockIdx.x * 256 + threadIdx.x;   // 65536 = 16*4096
  int b = g >> 12, n = g & 4095;
  const float* p = ixyz + (size_t)b * 12288;
  xyzT[g] = make_float4(p[n], p[4096 + n], p[8192 + n], 0.f);
}

// ---- main fused layer kernel ----
template<int KSTEPS, int OCH, bool GATHER, bool MAXOUT>
__global__ __launch_bounds__(256) void gemm_layer(
    const u16* __restrict__ xsrc, const float4* __restrict__ xyzT,
    const float* __restrict__ oxyz, const int* __restrict__ nbr,
    const u16* __restrict__ Wb, const float* __restrict__ ssin,
    u16* __restrict__ yout, float* __restrict__ gmax, float* __restrict__ gmin,
    float* __restrict__ stats) {
  constexpr int NT = OCH / 16;
  constexpr int PY = OCH + 2;
  __shared__ u16 xs[64 * 100];
  __shared__ u16 wsh[OCH * 100];
  __shared__ u16 ys[64 * PY];
  __shared__ float red[512];
  __shared__ float ss[128];

  const int t = threadIdx.x;
  const int blk = blockIdx.x;
  const int P0 = blk * 64;

  { // W -> LDS (already bf16/padded, same pitch)
    const u32* src = (const u32*)Wb;
    u32* dst = (u32*)wsh;
    for (int i = t; i < OCH * 50; i += 256) dst[i] = src[i];
  }
  if (!GATHER) {
    if (t < 128) ss[t] = ssin[t];
    __syncthreads();
  }

  // build x tile: 4 threads per point row
  const int m = t >> 2, s = t & 3;
  const int P = P0 + m;
  u16* xrow = xs + m * 100 + s * 16;
  if (GATHER) {
    const int b  = P >> 15;
    const int n2 = (P & 32767) >> 5;
    const int id = nbr[P];
    const uint4* frow = (const uint4*)(xsrc + (((size_t)b << 12) + id) * 64);
    uint4 f0 = frow[s * 2 + 0];
    uint4 f1 = frow[s * 2 + 1];
    *(uint2*)(xrow + 0)  = make_uint2(f0.x, f0.y);
    *(uint2*)(xrow + 4)  = make_uint2(f0.z, f0.w);
    *(uint2*)(xrow + 8)  = make_uint2(f1.x, f1.y);
    *(uint2*)(xrow + 12) = make_uint2(f1.z, f1.w);
    if (s == 0) {
      float4 p = xyzT[(b << 12) + id];
      float ox = oxyz[(b * 3 + 0) * 1024 + n2];
      float oy = oxyz[(b * 3 + 1) * 1024 + n2];
      float oz = oxyz[(b * 3 + 2) * 1024 + n2];
      u16* xr = xs + m * 100;
      xr[64] = f2b(p.x - ox); xr[65] = f2b(p.y - oy); xr[66] = f2b(p.z - oz);
    } else if (s == 1) {
      u16* xr = xs + m * 100;
      xr[67] = 0;
      #pragma unroll
      for (int j = 0; j < 8; ++j) *(uint2*)(xr + 68 + j * 4) = make_uint2(0, 0);
    }
  } else {
    const uint4* yrow = (const uint4*)(xsrc + ((size_t)P << 6));
    uint4 f0 = yrow[s * 2 + 0];
    uint4 f1 = yrow[s * 2 + 1];
    u32 w[8] = { f0.x, f0.y, f0.z, f0.w, f1.x, f1.y, f1.z, f1.w };
    u16 ov[16];
    #pragma unroll
    for (int i = 0; i < 8; ++i) {
      const int c = s * 16 + i * 2;
      float lo = b2f((u16)(w[i] & 0xffffu));
      float hi = b2f((u16)(w[i] >> 16));
      lo = fmaxf(lo * ss[c]     + ss[64 + c],     0.f);
      hi = fmaxf(hi * ss[c + 1] + ss[64 + c + 1], 0.f);
      ov[i * 2 + 0] = f2b(lo);
      ov[i * 2 + 1] = f2b(hi);
    }
    #pragma unroll
    for (int j = 0; j < 4; ++j) *(uint2*)(xrow + j * 4) = *(const uint2*)(ov + j * 4);
  }
  __syncthreads();

  // MFMA: D[m][o] = sum_k x[m][k] * W[o][k]
  floatx4 zero = {0.f, 0.f, 0.f, 0.f};
  floatx4 acc[NT];
  #pragma unroll
  for (int i = 0; i < NT; ++i) acc[i] = zero;
  const int lane = t & 63, wv = t >> 6;
  const int lr = lane & 15, quad = lane >> 4;
  const u16* ap = xs  + (wv * 16 + lr) * 100 + quad * 8;
  const u16* bp = wsh + lr * 100 + quad * 8;
  #pragma unroll
  for (int ks = 0; ks < KSTEPS; ++ks) {
    short8 av = ld_frag8(ap + ks * 32);
    #pragma unroll
    for (int nt = 0; nt < NT; ++nt) {
      short8 bv = ld_frag8(bp + nt * 1600 + ks * 32);
      acc[nt] = __builtin_amdgcn_mfma_f32_16x16x32_bf16(av, bv, acc[nt], 0, 0, 0);
    }
  }
  #pragma unroll
  for (int nt = 0; nt < NT; ++nt)
    #pragma unroll
    for (int r = 0; r < 4; ++r)
      ys[(wv * 16 + quad * 4 + r) * PY + nt * 16 + lr] = f2b(acc[nt][r]);
  __syncthreads();

  const int bucket = blk & (NBUK - 1);
  if (!MAXOUT) {
    { // per-channel partial sums over 64 rows (OCH==64)
      const int c = t & 63, seg = t >> 6;
      float s1 = 0.f, s2 = 0.f;
      for (int i = 0; i < 16; ++i) {
        float v = b2f(ys[(seg * 16 + i) * PY + c]);
        s1 += v; s2 += v * v;
      }
      red[seg * 64 + c] = s1;
      red[256 + seg * 64 + c] = s2;
    }
    { // write y tile coalesced
      u32* yo = (u32*)yout;
      #pragma unroll
      for (int i = 0; i < 8; ++i) {
        int flat = t + i * 256;          // 2048 uints
        int row = flat >> 5, cu = flat & 31;
        u32 v = *(const u32*)(ys + row * PY + cu * 2);
        yo[(size_t)(P0 + row) * 32 + cu] = v;
      }
    }
    __syncthreads();
    if (t < 64) {
      float s1 = red[t] + red[64 + t] + red[128 + t] + red[192 + t];
      float s2 = red[256 + t] + red[320 + t] + red[384 + t] + red[448 + t];
      atomicAdd(&stats[t * NBUK + bucket], s1);
      atomicAdd(&stats[128 * NBUK + t * NBUK + bucket], s2);
    }
  } else {
    const int c = t & 127, g = t >> 7;
    float s1 = 0.f, s2 = 0.f, mx = -INFINITY, mn = INFINITY;
    for (int i = 0; i < 32; ++i) {
      float v = b2f(ys[(g * 32 + i) * PY + c]);
      s1 += v; s2 += v * v; mx = fmaxf(mx, v); mn = fminf(mn, v);
    }
    const int prow = (P0 >> 5) + g;      // b*1024 + n2
    gmax[(size_t)prow * 128 + c] = mx;
    gmin[(size_t)prow * 128 + c] = mn;
    red[g * 128 + c] = s1;
    red[256 + g * 128 + c] = s2;
    __syncthreads();
    if (t < 128) {
      float s1 = red[t] + red[128 + t];
      float s2 = red[256 + t] + red[384 + t];
      atomicAdd(&stats[t * NBUK + bucket], s1);
      atomicAdd(&stats[128 * NBUK + t * NBUK + bucket], s2);
    }
  }
}

__global__ void finalize_stats(const float* __restrict__ stats, const float* __restrict__ gam,
                               const float* __restrict__ bet, float* __restrict__ ssout, int och) {
  int c = threadIdx.x;
  if (c >= och) return;
  float s1 = 0.f, s2 = 0.f;
  for (int j = 0; j < NBUK; ++j) {
    s1 += stats[c * NBUK + j];
    s2 += stats[128 * NBUK + c * NBUK + j];
  }
  const float invN = 1.f / (float)NPTS;
  float mean = s1 * invN;
  float var  = fmaxf(s2 * invN - mean * mean, 0.f);
  float scale = gam[c] * rsqrtf(var + 1e-5f);
  ssout[c] = scale;
  ssout[och + c] = bet[c] - mean * scale;
}

// ---- final: BN2 + relu on max/min, transpose to [b][c][n2] ----
__global__ __launch_bounds__(256) void final_out(const float* __restrict__ gmax,
                                                 const float* __restrict__ gmin,
                                                 const float* __restrict__ ss2,
                                                 float* __restrict__ out) {
  __shared__ float tile[64 * 33];
  int blk = blockIdx.x;                 // 1024 = 16 * 4 * 16
  int b = blk >> 6, rem = blk & 63, cc = rem >> 4, nn = rem & 15;
  int t = threadIdx.x;
  #pragma unroll
  for (int i = 0; i < 8; ++i) {
    int flat = t + i * 256;             // 2048
    int n2l = flat >> 5, cl = flat & 31;
    int c = cc * 32 + cl;
    size_t idx = (size_t)((b << 10) + nn * 64 + n2l) * 128 + c;
    float sc = ss2[c], sh = ss2[128 + c];
    float v = (sc >= 0.f) ? gmax[idx] : gmin[idx];
    tile[n2l * 33 + cl] = fmaxf(sc * v + sh, 0.f);
  }
  __syncthreads();
  #pragma unroll
  for (int i = 0; i < 8; ++i) {
    int flat = t + i * 256;
    int cl = flat >> 6, n2l = flat & 63;
    out[(size_t)((b * 128) + cc * 32 + cl) * 1024 + nn * 64 + n2l] = tile[n2l * 33 + cl];
  }
}

extern "C" void kernel_launch(void* const* d_in, const int* in_sizes, int n_in,
                              void* d_out, int out_size, void* d_ws, size_t ws_size,
                              hipStream_t stream) {
  const float* in_xyz  = (const float*)d_in[0];
  const float* out_xyz = (const float*)d_in[1];
  const float* in_feat = (const float*)d_in[2];
  const int*   nbr     = (const int*)d_in[3];
  const float* W0 = (const float*)d_in[4];
  const float* g0 = (const float*)d_in[5];
  const float* b0 = (const float*)d_in[6];
  const float* W1 = (const float*)d_in[7];
  const float* g1 = (const float*)d_in[8];
  const float* b1 = (const float*)d_in[9];
  const float* W2 = (const float*)d_in[10];
  const float* g2 = (const float*)d_in[11];
  const float* b2 = (const float*)d_in[12];
  float* out = (float*)d_out;

  char* ws = (char*)d_ws;
  float*  stats = (float*)(ws + 0);            // 3 * [2][128][64] f32 = 196608 B
  float*  ssbuf = (float*)(ws + 196608);       // 3 * 256 f32
  u16*    Wb    = (u16*)(ws + 200704);         // 25600 u16
  u16*    featT = (u16*)(ws + 262144);         // 8 MB
  float4* xyzT  = (float4*)(ws + 8650752);     // 1 MB
  u16*    y0    = (u16*)(ws + 9699328);        // 64 MB
  u16*    y1    = (u16*)(ws + 76808192);       // 64 MB
  float*  gmaxb = (float*)(ws + 143917056);    // 8 MB
  float*  gminb = (float*)(ws + 152305664);    // 8 MB (total ~161 MB)

  hipMemsetAsync(stats, 0, 196608, stream);
  hipLaunchKernelGGL(prep_w, dim3(100), dim3(256), 0, stream, W0, W1, W2, Wb);
  hipLaunchKernelGGL(trans_feat, dim3(4096), dim3(256), 0, stream, in_feat, featT);
  hipLaunchKernelGGL(trans_xyz, dim3(256), dim3(256), 0, stream, in_xyz, xyzT);

  hipLaunchKernelGGL((gemm_layer<3, 64, true, false>), dim3(8192), dim3(256), 0, stream,
                     featT, xyzT, out_xyz, nbr, Wb, nullptr, y0, nullptr, nullptr, stats);
  hipLaunchKernelGGL(finalize_stats, dim3(1), dim3(128), 0, stream, stats, g0, b0, ssbuf, 64);

  hipLaunchKernelGGL((gemm_layer<2, 64, false, false>), dim3(8192), dim3(256), 0, stream,
                     y0, nullptr, nullptr, nullptr, Wb + 6400, ssbuf, y1, nullptr, nullptr,
                     stats + 16384);
  hipLaunchKernelGGL(finalize_stats, dim3(1), dim3(128), 0, stream, stats + 16384, g1, b1,
                     ssbuf + 256, 64);

  hipLaunchKernelGGL((gemm_layer<2, 128, false, true>), dim3(8192), dim3(256), 0, stream,
                     y1, nullptr, nullptr, nullptr, Wb + 12800, ssbuf + 256, nullptr, gmaxb,
                     gminb, stats + 32768);
  hipLaunchKernelGGL(finalize_stats, dim3(1), dim3(128), 0, stream, stats + 32768, g2, b2,
                     ssbuf + 512, 128);

  hipLaunchKernelGGL(final_out, dim3(1024), dim3(256), 0, stream, gmaxb, gminb, ssbuf + 512, out);
}

// Round 2
// 286.948 us; speedup vs baseline: 1.5137x; 1.5137x over previous
//
#include <hip/hip_runtime.h>
#include <cstdint>

typedef unsigned short u16;
typedef unsigned int   u32;
typedef __attribute__((ext_vector_type(8))) short  short8;
typedef __attribute__((ext_vector_type(4))) float  floatx4;

#define NPTS 524288   // B*N2*K

__device__ __forceinline__ float b2f(u16 h) { return __uint_as_float(((u32)h) << 16); }
__device__ __forceinline__ u16 f2b(float f) {
  u32 u = __float_as_uint(f);
  return (u16)((u + 0x7FFFu + ((u >> 16) & 1u)) >> 16);
}
__device__ __forceinline__ short8 ld_frag8(const u16* p) {
  union { uint2 u[2]; short8 s; } x;
  x.u[0] = *(const uint2*)(p);
  x.u[1] = *(const uint2*)(p + 4);
  return x.s;
}

// ---- prep: W -> bf16, rows padded to pitch 100, zero pad region ----
__global__ __launch_bounds__(256) void prep_w(const float* __restrict__ W0,
                                              const float* __restrict__ W1,
                                              const float* __restrict__ W2,
                                              u16* __restrict__ Wb) {
  int s = blockIdx.x * 256 + threadIdx.x;   // 25600 total
  if (s >= 25600) return;
  u16 v = 0;
  if (s < 6400)        { int o = s / 100, c = s % 100; if (c < 67) v = f2b(W0[o * 67 + c]); }
  else if (s < 12800)  { int q = s - 6400;  int o = q / 100, c = q % 100; if (c < 64) v = f2b(W1[o * 64 + c]); }
  else                 { int q = s - 12800; int o = q / 100, c = q % 100; if (c < 64) v = f2b(W2[o * 64 + c]); }
  Wb[s] = v;
}

// ---- prep: in_feature [b][c][n] f32 -> featT [b][n][c] bf16 ----
__global__ __launch_bounds__(256) void trans_feat(const float* __restrict__ inf,
                                                  u16* __restrict__ featT) {
  __shared__ float tile[32 * 33];
  int blk = blockIdx.x;                 // 4096 = 16 * 2 * 128
  int b = blk >> 8, rem = blk & 255, cc = rem >> 7, nc = rem & 127;
  int t = threadIdx.x;
  #pragma unroll
  for (int i = 0; i < 4; ++i) {
    int flat = t + i * 256;             // 1024
    int cl = flat >> 5, nl = flat & 31;
    tile[cl * 33 + nl] = inf[(size_t)((b * 64) + cc * 32 + cl) * 4096 + nc * 32 + nl];
  }
  __syncthreads();
  #pragma unroll
  for (int i = 0; i < 4; ++i) {
    int flat = t + i * 256;
    int nl = flat >> 5, cl = flat & 31;
    featT[(size_t)((b << 12) + nc * 32 + nl) * 64 + cc * 32 + cl] = f2b(tile[cl * 33 + nl]);
  }
}

// ---- prep: in_xyz [b][3][n] -> xyzT [b][n][float4] ----
__global__ __launch_bounds__(256) void trans_xyz(const float* __restrict__ ixyz,
                                                 float4* __restrict__ xyzT) {
  int g = blockIdx.x * 256 + threadIdx.x;   // 65536 = 16*4096
  int b = g >> 12, n = g & 4095;
  const float* p = ixyz + (size_t)b * 12288;
  xyzT[g] = make_float4(p[n], p[4096 + n], p[8192 + n], 0.f);
}

// ---- main fused layer kernel (no atomics; per-block partial stats) ----
template<int KSTEPS, int OCH, bool GATHER, bool MAXOUT>
__global__ __launch_bounds__(256) void gemm_layer(
    const u16* __restrict__ xsrc, const float4* __restrict__ xyzT,
    const float* __restrict__ oxyz, const int* __restrict__ nbr,
    const u16* __restrict__ Wb, const float* __restrict__ ssin,
    u16* __restrict__ yout, float* __restrict__ gmax, float* __restrict__ gmin,
    float* __restrict__ partial) {
  constexpr int NT = OCH / 16;
  constexpr int PY = OCH + 2;
  __shared__ u16 xs[64 * 100];
  __shared__ u16 wsh[OCH * 100];
  __shared__ u16 ys[MAXOUT ? 2 : 64 * PY];
  __shared__ float red[8 * OCH];
  __shared__ float redm[MAXOUT ? 1024 : 4];
  __shared__ float ss[128];

  const int t = threadIdx.x;
  const int blk = blockIdx.x;
  const int P0 = blk * 64;

  { // W -> LDS (already bf16/padded, same pitch)
    const u32* src = (const u32*)Wb;
    u32* dst = (u32*)wsh;
    for (int i = t; i < OCH * 50; i += 256) dst[i] = src[i];
  }
  if (!GATHER) {
    if (t < 128) ss[t] = ssin[t];
    __syncthreads();
  }

  // build x tile: 4 threads per point row
  const int m = t >> 2, s = t & 3;
  const int P = P0 + m;
  u16* xrow = xs + m * 100 + s * 16;
  if (GATHER) {
    const int b  = P >> 15;
    const int n2 = (P & 32767) >> 5;
    const int id = nbr[P];
    const uint4* frow = (const uint4*)(xsrc + (((size_t)b << 12) + id) * 64);
    uint4 f0 = frow[s * 2 + 0];
    uint4 f1 = frow[s * 2 + 1];
    *(uint2*)(xrow + 0)  = make_uint2(f0.x, f0.y);
    *(uint2*)(xrow + 4)  = make_uint2(f0.z, f0.w);
    *(uint2*)(xrow + 8)  = make_uint2(f1.x, f1.y);
    *(uint2*)(xrow + 12) = make_uint2(f1.z, f1.w);
    if (s == 0) {
      float4 p = xyzT[(b << 12) + id];
      float ox = oxyz[(b * 3 + 0) * 1024 + n2];
      float oy = oxyz[(b * 3 + 1) * 1024 + n2];
      float oz = oxyz[(b * 3 + 2) * 1024 + n2];
      u16* xr = xs + m * 100;
      xr[64] = f2b(p.x - ox); xr[65] = f2b(p.y - oy); xr[66] = f2b(p.z - oz);
    } else if (s == 1) {
      u16* xr = xs + m * 100;
      xr[67] = 0;
      #pragma unroll
      for (int j = 0; j < 8; ++j) *(uint2*)(xr + 68 + j * 4) = make_uint2(0, 0);
    }
  } else {
    const uint4* yrow = (const uint4*)(xsrc + ((size_t)P << 6));
    uint4 f0 = yrow[s * 2 + 0];
    uint4 f1 = yrow[s * 2 + 1];
    u32 w[8] = { f0.x, f0.y, f0.z, f0.w, f1.x, f1.y, f1.z, f1.w };
    u16 ov[16];
    #pragma unroll
    for (int i = 0; i < 8; ++i) {
      const int c = s * 16 + i * 2;
      float lo = b2f((u16)(w[i] & 0xffffu));
      float hi = b2f((u16)(w[i] >> 16));
      lo = fmaxf(lo * ss[c]     + ss[64 + c],     0.f);
      hi = fmaxf(hi * ss[c + 1] + ss[64 + c + 1], 0.f);
      ov[i * 2 + 0] = f2b(lo);
      ov[i * 2 + 1] = f2b(hi);
    }
    #pragma unroll
    for (int j = 0; j < 4; ++j) *(uint2*)(xrow + j * 4) = *(const uint2*)(ov + j * 4);
  }
  __syncthreads();

  // MFMA: D[m][o] = sum_k x[m][k] * W[o][k]
  floatx4 zero = {0.f, 0.f, 0.f, 0.f};
  floatx4 acc[NT];
  #pragma unroll
  for (int i = 0; i < NT; ++i) acc[i] = zero;
  const int lane = t & 63, wv = t >> 6;
  const int lr = lane & 15, quad = lane >> 4;
  const u16* ap = xs  + (wv * 16 + lr) * 100 + quad * 8;
  const u16* bp = wsh + lr * 100 + quad * 8;
  #pragma unroll
  for (int ks = 0; ks < KSTEPS; ++ks) {
    short8 av = ld_frag8(ap + ks * 32);
    #pragma unroll
    for (int nt = 0; nt < NT; ++nt) {
      short8 bv = ld_frag8(bp + nt * 1600 + ks * 32);
      acc[nt] = __builtin_amdgcn_mfma_f32_16x16x32_bf16(av, bv, acc[nt], 0, 0, 0);
    }
  }

  // ---- stats (and max/min) straight from accumulator registers ----
  float s1[NT], s2[NT], mx[NT], mn[NT];
  #pragma unroll
  for (int nt = 0; nt < NT; ++nt) {
    float a0 = acc[nt][0], a1 = acc[nt][1], a2 = acc[nt][2], a3 = acc[nt][3];
    s1[nt] = (a0 + a1) + (a2 + a3);
    s2[nt] = (a0 * a0 + a1 * a1) + (a2 * a2 + a3 * a3);
    if (MAXOUT) {
      mx[nt] = fmaxf(fmaxf(a0, a1), fmaxf(a2, a3));
      mn[nt] = fminf(fminf(a0, a1), fminf(a2, a3));
    }
  }
  #pragma unroll
  for (int nt = 0; nt < NT; ++nt) {
    s1[nt] += __shfl_xor(s1[nt], 16); s1[nt] += __shfl_xor(s1[nt], 32);
    s2[nt] += __shfl_xor(s2[nt], 16); s2[nt] += __shfl_xor(s2[nt], 32);
    if (MAXOUT) {
      mx[nt] = fmaxf(mx[nt], __shfl_xor(mx[nt], 16));
      mx[nt] = fmaxf(mx[nt], __shfl_xor(mx[nt], 32));
      mn[nt] = fminf(mn[nt], __shfl_xor(mn[nt], 16));
      mn[nt] = fminf(mn[nt], __shfl_xor(mn[nt], 32));
    }
  }
  if (lane < 16) {
    #pragma unroll
    for (int nt = 0; nt < NT; ++nt) {
      int c = nt * 16 + lane;
      red[wv * OCH + c] = s1[nt];
      red[4 * OCH + wv * OCH + c] = s2[nt];
      if (MAXOUT) {
        redm[wv * 128 + c] = mx[nt];
        redm[512 + wv * 128 + c] = mn[nt];
      }
    }
  }
  if (!MAXOUT) {
    #pragma unroll
    for (int nt = 0; nt < NT; ++nt)
      #pragma unroll
      for (int r = 0; r < 4; ++r)
        ys[(wv * 16 + quad * 4 + r) * PY + nt * 16 + lr] = f2b(acc[nt][r]);
  }
  __syncthreads();

  if (!MAXOUT) {
    { // write y tile coalesced
      u32* yo = (u32*)yout;
      #pragma unroll
      for (int i = 0; i < 8; ++i) {
        int flat = t + i * 256;          // 2048 uints
        int row = flat >> 5, cu = flat & 31;
        yo[(size_t)(P0 + row) * 32 + cu] = *(const u32*)(ys + row * PY + cu * 2);
      }
    }
    if (t < OCH) {
      float a = red[t] + red[OCH + t] + red[2 * OCH + t] + red[3 * OCH + t];
      float b = red[4 * OCH + t] + red[5 * OCH + t] + red[6 * OCH + t] + red[7 * OCH + t];
      partial[(size_t)blk * (2 * OCH) + t] = a;
      partial[(size_t)blk * (2 * OCH) + OCH + t] = b;
    }
  } else {
    if (t < 128) {
      float a = red[t] + red[128 + t] + red[256 + t] + red[384 + t];
      float b = red[512 + t] + red[640 + t] + red[768 + t] + red[896 + t];
      partial[(size_t)blk * 256 + t] = a;
      partial[(size_t)blk * 256 + 128 + t] = b;
    }
    {
      int g = t >> 7, c = t & 127;
      float vmx = fmaxf(redm[(2 * g) * 128 + c], redm[(2 * g + 1) * 128 + c]);
      float vmn = fminf(redm[512 + (2 * g) * 128 + c], redm[512 + (2 * g + 1) * 128 + c]);
      int prow = (P0 >> 5) + g;          // b*1024 + n2
      gmax[(size_t)prow * 128 + c] = vmx;
      gmin[(size_t)prow * 128 + c] = vmn;
    }
  }
}

// ---- stage 1: reduce 8192 block-partials by 128 rows per block ----
__global__ __launch_bounds__(256) void reduce_partial(const float* __restrict__ partial,
                                                      float* __restrict__ tmp, int stride) {
  int r0 = blockIdx.x * 128;
  int t = threadIdx.x;
  for (int c = t; c < stride; c += 256) {
    float s = 0.f;
    for (int r = 0; r < 128; ++r) s += partial[(size_t)(r0 + r) * stride + c];
    tmp[blockIdx.x * stride + c] = s;
  }
}

// ---- stage 2: final mean/var -> scale/shift ----
__global__ void finalize_b(const float* __restrict__ tmp, const float* __restrict__ gam,
                           const float* __restrict__ bet, float* __restrict__ ssout, int och) {
  int c = threadIdx.x;
  if (c >= och) return;
  float s1 = 0.f, s2 = 0.f;
  for (int r = 0; r < 64; ++r) {
    s1 += tmp[r * 2 * och + c];
    s2 += tmp[r * 2 * och + och + c];
  }
  const float invN = 1.f / (float)NPTS;
  float mean = s1 * invN;
  float var  = fmaxf(s2 * invN - mean * mean, 0.f);
  float scale = gam[c] * rsqrtf(var + 1e-5f);
  ssout[c] = scale;
  ssout[och + c] = bet[c] - mean * scale;
}

// ---- final: BN2 + relu on max/min, transpose to [b][c][n2] ----
__global__ __launch_bounds__(256) void final_out(const float* __restrict__ gmax,
                                                 const float* __restrict__ gmin,
                                                 const float* __restrict__ ss2,
                                                 float* __restrict__ out) {
  __shared__ float tile[64 * 33];
  int blk = blockIdx.x;                 // 1024 = 16 * 4 * 16
  int b = blk >> 6, rem = blk & 63, cc = rem >> 4, nn = rem & 15;
  int t = threadIdx.x;
  #pragma unroll
  for (int i = 0; i < 8; ++i) {
    int flat = t + i * 256;             // 2048
    int n2l = flat >> 5, cl = flat & 31;
    int c = cc * 32 + cl;
    size_t idx = (size_t)((b << 10) + nn * 64 + n2l) * 128 + c;
    float sc = ss2[c], sh = ss2[128 + c];
    float v = (sc >= 0.f) ? gmax[idx] : gmin[idx];
    tile[n2l * 33 + cl] = fmaxf(sc * v + sh, 0.f);
  }
  __syncthreads();
  #pragma unroll
  for (int i = 0; i < 8; ++i) {
    int flat = t + i * 256;
    int cl = flat >> 6, n2l = flat & 63;
    out[(size_t)((b * 128) + cc * 32 + cl) * 1024 + nn * 64 + n2l] = tile[n2l * 33 + cl];
  }
}

extern "C" void kernel_launch(void* const* d_in, const int* in_sizes, int n_in,
                              void* d_out, int out_size, void* d_ws, size_t ws_size,
                              hipStream_t stream) {
  const float* in_xyz  = (const float*)d_in[0];
  const float* out_xyz = (const float*)d_in[1];
  const float* in_feat = (const float*)d_in[2];
  const int*   nbr     = (const int*)d_in[3];
  const float* W0 = (const float*)d_in[4];
  const float* g0 = (const float*)d_in[5];
  const float* b0 = (const float*)d_in[6];
  const float* W1 = (const float*)d_in[7];
  const float* g1 = (const float*)d_in[8];
  const float* b1 = (const float*)d_in[9];
  const float* W2 = (const float*)d_in[10];
  const float* g2 = (const float*)d_in[11];
  const float* b2 = (const float*)d_in[12];
  float* out = (float*)d_out;

  char* ws = (char*)d_ws;
  float*  ssbuf = (float*)(ws + 0);            // 768 f32 used (4 KB slot)
  u16*    Wb    = (u16*)(ws + 4096);           // 25600 u16
  float*  tmp0  = (float*)(ws + 57344);        // 64*128 f32
  float*  tmp1  = (float*)(ws + 122880);       // 64*128 f32
  float*  tmp2  = (float*)(ws + 188416);       // 64*256 f32
  u16*    featT = (u16*)(ws + 262144);         // 8 MiB
  float4* xyzT  = (float4*)(ws + 8650752);     // 1 MiB
  u16*    y0    = (u16*)(ws + 9699328);        // 64 MiB
  u16*    y1    = (u16*)(ws + 76808192);       // 64 MiB
  float*  gmaxb = (float*)(ws + 143917056);    // 8 MiB
  float*  gminb = (float*)(ws + 152305664);    // 8 MiB (total ~160.7 MB)
  // partial buffers aliased into provably-dead regions:
  float*  p0 = (float*)(ws + 76808192);        // in y1 area (y1 written only after p0 consumed)
  float*  p1 = (float*)(ws + 262144);          // in featT area (featT dead after L0)
  float*  p2 = (float*)(ws + 9699328);         // in y0 area (y0 dead after L1)

  hipLaunchKernelGGL(prep_w, dim3(100), dim3(256), 0, stream, W0, W1, W2, Wb);
  hipLaunchKernelGGL(trans_feat, dim3(4096), dim3(256), 0, stream, in_feat, featT);
  hipLaunchKernelGGL(trans_xyz, dim3(256), dim3(256), 0, stream, in_xyz, xyzT);

  hipLaunchKernelGGL((gemm_layer<3, 64, true, false>), dim3(8192), dim3(256), 0, stream,
                     featT, xyzT, out_xyz, nbr, Wb, nullptr, y0, nullptr, nullptr, p0);
  hipLaunchKernelGGL(reduce_partial, dim3(64), dim3(256), 0, stream, p0, tmp0, 128);
  hipLaunchKernelGGL(finalize_b, dim3(1), dim3(128), 0, stream, tmp0, g0, b0, ssbuf, 64);

  hipLaunchKernelGGL((gemm_layer<2, 64, false, false>), dim3(8192), dim3(256), 0, stream,
                     y0, nullptr, nullptr, nullptr, Wb + 6400, ssbuf, y1, nullptr, nullptr, p1);
  hipLaunchKernelGGL(reduce_partial, dim3(64), dim3(256), 0, stream, p1, tmp1, 128);
  hipLaunchKernelGGL(finalize_b, dim3(1), dim3(128), 0, stream, tmp1, g1, b1, ssbuf + 256, 64);

  hipLaunchKernelGGL((gemm_layer<2, 128, false, true>), dim3(8192), dim3(256), 0, stream,
                     y1, nullptr, nullptr, nullptr, Wb + 12800, ssbuf + 256, nullptr, gmaxb,
                     gminb, p2);
  hipLaunchKernelGGL(reduce_partial, dim3(64), dim3(256), 0, stream, p2, tmp2, 256);
  hipLaunchKernelGGL(finalize_b, dim3(1), dim3(128), 0, stream, tmp2, g2, b2, ssbuf + 512, 128);

  hipLaunchKernelGGL(final_out, dim3(1024), dim3(256), 0, stream, gmaxb, gminb, ssbuf + 512, out);
}

// Round 3
// 238.431 us; speedup vs baseline: 1.8218x; 1.2035x over previous
//
#include <hip/hip_runtime.h>
#include <cstdint>

typedef unsigned short u16;
typedef unsigned int   u32;
typedef __attribute__((ext_vector_type(8))) short  short8;
typedef __attribute__((ext_vector_type(4))) float  floatx4;

#define NPTS 524288   // B*N2*K

__device__ __forceinline__ float b2f(u16 h) { return __uint_as_float(((u32)h) << 16); }
__device__ __forceinline__ u16 f2b(float f) {
  u32 u = __float_as_uint(f);
  return (u16)((u + 0x7FFFu + ((u >> 16) & 1u)) >> 16);
}
__device__ __forceinline__ short8 ld_frag8(const u16* p) {
  union { uint4 q; short8 s; } x;
  x.q = *(const uint4*)p;
  return x.s;
}

// ---- combined prep: featT transpose + xyzT transpose + W->bf16 padded ----
// W layout in Wb: W0 64 rows x pitch104 @0 ; W1 64 x pitch72 @6656 ; W2 128 x pitch72 @11264
__global__ __launch_bounds__(256) void prep_all(const float* __restrict__ inf,
                                                const float* __restrict__ ixyz,
                                                const float* __restrict__ W0,
                                                const float* __restrict__ W1,
                                                const float* __restrict__ W2,
                                                u16* __restrict__ featT,
                                                float4* __restrict__ xyzT,
                                                u16* __restrict__ Wb) {
  __shared__ float tile[32 * 33];
  const int bk = blockIdx.x, t = threadIdx.x;
  if (bk < 4096) {          // in_feature [b][c][n] f32 -> featT [b][n][c] bf16
    int b = bk >> 8, rem = bk & 255, cc = rem >> 7, nc = rem & 127;
    #pragma unroll
    for (int i = 0; i < 4; ++i) {
      int flat = t + i * 256;
      int cl = flat >> 5, nl = flat & 31;
      tile[cl * 33 + nl] = inf[(size_t)((b * 64) + cc * 32 + cl) * 4096 + nc * 32 + nl];
    }
    __syncthreads();
    #pragma unroll
    for (int i = 0; i < 4; ++i) {
      int flat = t + i * 256;
      int nl = flat >> 5, cl = flat & 31;
      featT[(size_t)((b << 12) + nc * 32 + nl) * 64 + cc * 32 + cl] = f2b(tile[cl * 33 + nl]);
    }
  } else if (bk < 4352) {   // in_xyz [b][3][n] -> xyzT [b][n][float4]
    int g = (bk - 4096) * 256 + t;
    int b = g >> 12, n = g & 4095;
    const float* p = ixyz + (size_t)b * 12288;
    xyzT[g] = make_float4(p[n], p[4096 + n], p[8192 + n], 0.f);
  } else {                  // weights
    int s = (bk - 4352) * 256 + t;   // < 20480
    u16 v = 0;
    if (s < 6656)       { int o = s / 104, c = s % 104; if (c < 67) v = f2b(W0[o * 67 + c]); }
    else if (s < 11264) { int q = s - 6656;  int o = q / 72, c = q % 72; if (c < 64) v = f2b(W1[o * 64 + c]); }
    else                { int q = s - 11264; int o = q / 72, c = q % 72; if (c < 64) v = f2b(W2[o * 64 + c]); }
    Wb[s] = v;
  }
}

// ---- main fused layer: M=256 rows/block, 4 pipelined subtiles of 64 ----
template<int KSTEPS, int OCH, bool GATHER, bool MAXOUT>
__global__ __launch_bounds__(256, 4) void gemm_layer(
    const u16* __restrict__ xsrc, const float4* __restrict__ xyzT,
    const float* __restrict__ oxyz, const int* __restrict__ nbr,
    const u16* __restrict__ Wb, const float* __restrict__ ssin,
    u16* __restrict__ yout, float* __restrict__ gmax, float* __restrict__ gmin,
    float* __restrict__ partial) {
  constexpr int PITCH = KSTEPS * 32 + 8;   // 104 (K=96) or 72 (K=64): <=2-way LDS aliasing
  constexpr int NT = OCH / 16;
  __shared__ __align__(16) u16 wsh[OCH * PITCH];
  __shared__ __align__(16) u16 xs[64 * PITCH];
  __shared__ float red[8 * OCH];
  __shared__ float redm[MAXOUT ? 1024 : 4];
  __shared__ float ss[GATHER ? 4 : 128];

  const int t = threadIdx.x;
  const int blk = blockIdx.x;
  const int P0 = blk * 256;
  const int lane = t & 63, wv = t >> 6;
  const int lr = lane & 15, quad = lane >> 4;
  const int m = t >> 2, s4 = t & 3;

  { // W -> LDS (counts divide 256 exactly for all instantiations)
    const u32* src = (const u32*)Wb;
    u32* dst = (u32*)wsh;
    constexpr int NW = OCH * PITCH / 2;
    #pragma unroll
    for (int i = 0; i < NW / 256; ++i) dst[t + i * 256] = src[t + i * 256];
  }
  if constexpr (!GATHER) {
    if (t < 128) ss[t] = ssin[t];
    __syncthreads();          // publish ss before first commit uses it
  }

  int idx4[4];
  if constexpr (GATHER) {
    #pragma unroll
    for (int sub = 0; sub < 4; ++sub) idx4[sub] = nbr[P0 + sub * 64 + m];
  }

  uint4 f0, f1;
  float sx = 0.f, sy = 0.f, sz = 0.f;

  auto issue = [&](int sub) {
    const int P = P0 + sub * 64 + m;
    if constexpr (GATHER) {
      const int b = P >> 15;
      const int id = idx4[sub];
      const uint4* frow = (const uint4*)(xsrc + (((size_t)b << 12) + id) * 64);
      f0 = frow[s4 * 2 + 0];
      f1 = frow[s4 * 2 + 1];
      if (s4 == 0) {
        const int n2 = (P & 32767) >> 5;
        float4 p = xyzT[(b << 12) + id];
        sx = p.x - oxyz[(b * 3 + 0) * 1024 + n2];
        sy = p.y - oxyz[(b * 3 + 1) * 1024 + n2];
        sz = p.z - oxyz[(b * 3 + 2) * 1024 + n2];
      }
    } else {
      const uint4* yrow = (const uint4*)(xsrc + ((size_t)P << 6));
      f0 = yrow[s4 * 2 + 0];
      f1 = yrow[s4 * 2 + 1];
    }
  };

  auto commit = [&]() {
    u16* xrow = xs + m * PITCH + s4 * 16;
    if constexpr (GATHER) {
      *(uint4*)(xrow + 0) = f0;
      *(uint4*)(xrow + 8) = f1;
      if (s4 == 0) {
        u16* xr = xs + m * PITCH;
        xr[64] = f2b(sx); xr[65] = f2b(sy); xr[66] = f2b(sz);
      }
    } else {
      u32 w[8] = { f0.x, f0.y, f0.z, f0.w, f1.x, f1.y, f1.z, f1.w };
      u16 ov[16];
      #pragma unroll
      for (int i = 0; i < 8; ++i) {
        const int c = s4 * 16 + i * 2;
        float lo = b2f((u16)(w[i] & 0xffffu));
        float hi = b2f((u16)(w[i] >> 16));
        lo = fmaxf(lo * ss[c]     + ss[64 + c],     0.f);
        hi = fmaxf(hi * ss[c + 1] + ss[64 + c + 1], 0.f);
        ov[i * 2 + 0] = f2b(lo);
        ov[i * 2 + 1] = f2b(hi);
      }
      *(uint4*)(xrow + 0) = *(const uint4*)(ov + 0);
      *(uint4*)(xrow + 8) = *(const uint4*)(ov + 8);
    }
  };

  issue(0);
  commit();
  if constexpr (GATHER) {   // zero pad chans 67..103 once; survives subtile reuse
    if (s4 == 1) {
      u16* xr = xs + m * PITCH;
      xr[67] = 0;
      #pragma unroll
      for (int j = 0; j < 9; ++j) *(uint2*)(xr + 68 + j * 4) = make_uint2(0u, 0u);
    }
  }
  __syncthreads();

  float s1[NT], s2[NT];
  #pragma unroll
  for (int nt = 0; nt < NT; ++nt) { s1[nt] = 0.f; s2[nt] = 0.f; }

  const u16* ap = xs + (wv * 16 + lr) * PITCH + quad * 8;
  const u16* bp = wsh + lr * PITCH + quad * 8;
  u32* yo32 = (u32*)yout;

  for (int sub = 0; sub < 4; ++sub) {
    if (sub < 3) issue(sub + 1);   // loads in flight during MFMA + epilogue

    floatx4 acc[NT];
    #pragma unroll
    for (int nt = 0; nt < NT; ++nt) acc[nt] = (floatx4){0.f, 0.f, 0.f, 0.f};
    #pragma unroll
    for (int ks = 0; ks < KSTEPS; ++ks) {
      short8 av = ld_frag8(ap + ks * 32);
      #pragma unroll
      for (int nt = 0; nt < NT; ++nt) {
        short8 bv = ld_frag8(bp + nt * 16 * PITCH + ks * 32);
        acc[nt] = __builtin_amdgcn_mfma_f32_16x16x32_bf16(av, bv, acc[nt], 0, 0, 0);
      }
    }

    #pragma unroll
    for (int nt = 0; nt < NT; ++nt) {
      float a0 = acc[nt][0], a1 = acc[nt][1], a2 = acc[nt][2], a3 = acc[nt][3];
      s1[nt] += (a0 + a1) + (a2 + a3);
      s2[nt] += (a0 * a0 + a1 * a1) + (a2 * a2 + a3 * a3);
    }

    if constexpr (!MAXOUT) {
      // direct y store from accs: pack channel pairs via xor-1 shuffle
      const int R0 = P0 + sub * 64 + wv * 16 + quad * 4;
      #pragma unroll
      for (int nt = 0; nt < NT; ++nt) {
        #pragma unroll
        for (int r = 0; r < 4; ++r) {
          u32 h = (u32)f2b(acc[nt][r]);
          u32 o = (u32)__shfl_xor((int)h, 1);
          if ((lr & 1) == 0)
            yo32[(size_t)(R0 + r) * (OCH / 2) + nt * 8 + (lr >> 1)] = h | (o << 16);
        }
      }
      __syncthreads();              // all MFMA reads of xs done
      if (sub < 3) commit();        // write next subtile
      __syncthreads();
    } else {
      float mx[NT], mn[NT];
      #pragma unroll
      for (int nt = 0; nt < NT; ++nt) {
        mx[nt] = fmaxf(fmaxf(acc[nt][0], acc[nt][1]), fmaxf(acc[nt][2], acc[nt][3]));
        mn[nt] = fminf(fminf(acc[nt][0], acc[nt][1]), fminf(acc[nt][2], acc[nt][3]));
        mx[nt] = fmaxf(mx[nt], __shfl_xor(mx[nt], 16));
        mx[nt] = fmaxf(mx[nt], __shfl_xor(mx[nt], 32));
        mn[nt] = fminf(mn[nt], __shfl_xor(mn[nt], 16));
        mn[nt] = fminf(mn[nt], __shfl_xor(mn[nt], 32));
      }
      if (lane < 16) {
        #pragma unroll
        for (int nt = 0; nt < NT; ++nt) {
          redm[wv * 128 + nt * 16 + lr] = mx[nt];
          redm[512 + wv * 128 + nt * 16 + lr] = mn[nt];
        }
      }
      __syncthreads();              // redm ready + MFMA reads of xs done
      {
        const int g = t >> 7, c = t & 127;
        float vmx = fmaxf(redm[(2 * g) * 128 + c], redm[(2 * g + 1) * 128 + c]);
        float vmn = fminf(redm[512 + (2 * g) * 128 + c], redm[512 + (2 * g + 1) * 128 + c]);
        const int prow = blk * 8 + sub * 2 + g;   // b*1024+n2
        gmax[(size_t)prow * 128 + c] = vmx;
        gmin[(size_t)prow * 128 + c] = vmn;
      }
      if (sub < 3) commit();
      __syncthreads();
    }
  }

  // final per-block stats reduction
  #pragma unroll
  for (int nt = 0; nt < NT; ++nt) {
    s1[nt] += __shfl_xor(s1[nt], 16); s1[nt] += __shfl_xor(s1[nt], 32);
    s2[nt] += __shfl_xor(s2[nt], 16); s2[nt] += __shfl_xor(s2[nt], 32);
  }
  if (lane < 16) {
    #pragma unroll
    for (int nt = 0; nt < NT; ++nt) {
      red[wv * OCH + nt * 16 + lr] = s1[nt];
      red[4 * OCH + wv * OCH + nt * 16 + lr] = s2[nt];
    }
  }
  __syncthreads();
  if (t < OCH) {
    float a = red[t] + red[OCH + t] + red[2 * OCH + t] + red[3 * OCH + t];
    float b = red[4 * OCH + t] + red[5 * OCH + t] + red[6 * OCH + t] + red[7 * OCH + t];
    partial[(size_t)blk * (2 * OCH) + t] = a;
    partial[(size_t)blk * (2 * OCH) + OCH + t] = b;
  }
}

// ---- single-kernel stats reduce + finalize: partial[2048][2*OCH] -> scale/shift ----
template<int OCH>
__global__ __launch_bounds__(1024) void stats_finalize(const float* __restrict__ partial,
                                                       const float* __restrict__ gam,
                                                       const float* __restrict__ bet,
                                                       float* __restrict__ ssout) {
  constexpr int COLS = 2 * OCH;
  constexpr int SEGS = 1024 / COLS;
  __shared__ float lds[1024];
  const int t = threadIdx.x;
  const int c = t & (COLS - 1), seg = t / COLS;
  float s = 0.f;
  #pragma unroll 8
  for (int r = seg; r < 2048; r += SEGS) s += partial[(size_t)r * COLS + c];
  lds[t] = s;
  __syncthreads();
  if (seg == 0) {
    #pragma unroll
    for (int j = 1; j < SEGS; ++j) s += lds[j * COLS + c];
    lds[c] = s;
  }
  __syncthreads();
  if (t < OCH) {
    const float invN = 1.f / (float)NPTS;
    float mean = lds[t] * invN;
    float var  = fmaxf(lds[OCH + t] * invN - mean * mean, 0.f);
    float scale = gam[t] * rsqrtf(var + 1e-5f);
    ssout[t] = scale;
    ssout[OCH + t] = bet[t] - mean * scale;
  }
}

// ---- final: BN2 + relu on max/min, transpose to [b][c][n2] ----
__global__ __launch_bounds__(256) void final_out(const float* __restrict__ gmax,
                                                 const float* __restrict__ gmin,
                                                 const float* __restrict__ ss2,
                                                 float* __restrict__ out) {
  __shared__ float tile[64 * 33];
  int blk = blockIdx.x;                 // 1024 = 16 * 4 * 16
  int b = blk >> 6, rem = blk & 63, cc = rem >> 4, nn = rem & 15;
  int t = threadIdx.x;
  #pragma unroll
  for (int i = 0; i < 8; ++i) {
    int flat = t + i * 256;             // 2048
    int n2l = flat >> 5, cl = flat & 31;
    int c = cc * 32 + cl;
    size_t idx = (size_t)((b << 10) + nn * 64 + n2l) * 128 + c;
    float sc = ss2[c], sh = ss2[128 + c];
    float v = (sc >= 0.f) ? gmax[idx] : gmin[idx];
    tile[n2l * 33 + cl] = fmaxf(sc * v + sh, 0.f);
  }
  __syncthreads();
  #pragma unroll
  for (int i = 0; i < 8; ++i) {
    int flat = t + i * 256;
    int cl = flat >> 6, n2l = flat & 63;
    out[(size_t)((b * 128) + cc * 32 + cl) * 1024 + nn * 64 + n2l] = tile[n2l * 33 + cl];
  }
}

extern "C" void kernel_launch(void* const* d_in, const int* in_sizes, int n_in,
                              void* d_out, int out_size, void* d_ws, size_t ws_size,
                              hipStream_t stream) {
  const float* in_xyz  = (const float*)d_in[0];
  const float* out_xyz = (const float*)d_in[1];
  const float* in_feat = (const float*)d_in[2];
  const int*   nbr     = (const int*)d_in[3];
  const float* W0 = (const float*)d_in[4];
  const float* g0 = (const float*)d_in[5];
  const float* b0 = (const float*)d_in[6];
  const float* W1 = (const float*)d_in[7];
  const float* g1 = (const float*)d_in[8];
  const float* b1 = (const float*)d_in[9];
  const float* W2 = (const float*)d_in[10];
  const float* g2 = (const float*)d_in[11];
  const float* b2 = (const float*)d_in[12];
  float* out = (float*)d_out;

  char* ws = (char*)d_ws;
  float*  ssbuf = (float*)(ws + 0);            // 768 f32
  u16*    Wb    = (u16*)(ws + 4096);           // 20480 u16 = 40960 B
  u16*    featT = (u16*)(ws + 262144);         // 8 MiB
  float4* xyzT  = (float4*)(ws + 8650752);     // 1 MiB
  u16*    y0    = (u16*)(ws + 9699328);        // 64 MiB
  u16*    y1    = (u16*)(ws + 76808192);       // 64 MiB
  float*  gmaxb = (float*)(ws + 143917056);    // 8 MiB
  float*  gminb = (float*)(ws + 152305664);    // 8 MiB (total ~160.7 MB)
  // partial buffers aliased into dead regions:
  float*  p0 = (float*)(ws + 76808192);        // in y1 area (consumed before y1 written)
  float*  p1 = (float*)(ws + 262144);          // in featT area (featT dead after L0)
  float*  p2 = (float*)(ws + 9699328);         // in y0 area (y0 dead after L1)

  hipLaunchKernelGGL(prep_all, dim3(4432), dim3(256), 0, stream,
                     in_feat, in_xyz, W0, W1, W2, featT, xyzT, Wb);

  hipLaunchKernelGGL((gemm_layer<3, 64, true, false>), dim3(2048), dim3(256), 0, stream,
                     featT, xyzT, out_xyz, nbr, Wb, nullptr, y0, nullptr, nullptr, p0);
  hipLaunchKernelGGL((stats_finalize<64>), dim3(1), dim3(1024), 0, stream, p0, g0, b0, ssbuf);

  hipLaunchKernelGGL((gemm_layer<2, 64, false, false>), dim3(2048), dim3(256), 0, stream,
                     y0, nullptr, nullptr, nullptr, Wb + 6656, ssbuf, y1, nullptr, nullptr, p1);
  hipLaunchKernelGGL((stats_finalize<64>), dim3(1), dim3(1024), 0, stream, p1, g1, b1, ssbuf + 256);

  hipLaunchKernelGGL((gemm_layer<2, 128, false, true>), dim3(2048), dim3(256), 0, stream,
                     y1, nullptr, nullptr, nullptr, Wb + 11264, ssbuf + 256, nullptr, gmaxb,
                     gminb, p2);
  hipLaunchKernelGGL((stats_finalize<128>), dim3(1), dim3(1024), 0, stream, p2, g2, b2, ssbuf + 512);

  hipLaunchKernelGGL(final_out, dim3(1024), dim3(256), 0, stream, gmaxb, gminb, ssbuf + 512, out);
}